// Round 10
// baseline (315.014 us; speedup 1.0000x reference)
//
#include <hip/hip_runtime.h>
#include <stdint.h>

// ---------------------------------------------------------------------------
// Types / helpers
// ---------------------------------------------------------------------------
typedef __bf16 bf16x8 __attribute__((ext_vector_type(8)));
typedef float  f32x4  __attribute__((ext_vector_type(4)));

__device__ __forceinline__ unsigned short f2bf(float f) {
  union { float f; unsigned int u; } a; a.f = f;
  unsigned int r = a.u + 0x7FFFu + ((a.u >> 16) & 1u);   // RNE
  return (unsigned short)(r >> 16);
}

__device__ __forceinline__ unsigned short f2bf_fast(float f) {
  union { __bf16 b; unsigned short u; } v; v.b = (__bf16)f; return v.u;
}

// async global->LDS, 16B per lane. LDS dest must be wave-uniform base + lane*16.
__device__ __forceinline__ void cp16(const void* g, void* l) {
  auto g1 = reinterpret_cast<__attribute__((address_space(1))) unsigned int*>(
      reinterpret_cast<uintptr_t>(g));
  auto l3 = reinterpret_cast<__attribute__((address_space(3))) unsigned int*>(
      reinterpret_cast<uintptr_t>(l));
  __builtin_amdgcn_global_load_lds(g1, l3, 16, 0, 0);
}

__device__ __forceinline__ void cvt4(const float* src, unsigned short* dst, int i) {
  float4 v = *(const float4*)(src + i);
  union { unsigned short u[4]; uint2 p; } o;
  o.u[0] = f2bf(v.x); o.u[1] = f2bf(v.y); o.u[2] = f2bf(v.z); o.u[3] = f2bf(v.w);
  *(uint2*)(dst + i) = o.p;
}

// ---------------------------------------------------------------------------
// R10: cvt_ln1 now converts ONLY ipw (blocks 0..3071, needed immediately by
// QKV) + ln1 (blocks 3072..7167). outw/w1/w2 converts moved into qkv_cvt
// (trailing blocks backfill the GEMM drain tail -> overlapped, not serial).
// ---------------------------------------------------------------------------
__global__ __launch_bounds__(256) void cvt_ln1(
    const float* __restrict__ s0,
    unsigned short* __restrict__ d0,
    const float* __restrict__ x,
    const float* __restrict__ g,
    const float* __restrict__ bta,
    unsigned short* __restrict__ out) {
  if (blockIdx.x < 3072) {
    cvt4(s0, d0, (blockIdx.x * 256 + threadIdx.x) * 4);
    return;
  }
  const int row = blockIdx.x - 3072, t = threadIdx.x;
  const float4 v = *(const float4*)(x + (size_t)row * 1024 + t * 4);
  float s1v = v.x + v.y + v.z + v.w;
  float s2v = v.x*v.x + v.y*v.y + v.z*v.z + v.w*v.w;
  #pragma unroll
  for (int off = 1; off < 64; off <<= 1) {
    s1v += __shfl_xor(s1v, off, 64);
    s2v += __shfl_xor(s2v, off, 64);
  }
  __shared__ float r1[4], r2[4];
  if ((t & 63) == 0) { r1[t >> 6] = s1v; r2[t >> 6] = s2v; }
  __syncthreads();
  s1v = r1[0] + r1[1] + r1[2] + r1[3];
  s2v = r2[0] + r2[1] + r2[2] + r2[3];
  const float mean = s1v * (1.0f / 1024.0f);
  const float var  = s2v * (1.0f / 1024.0f) - mean * mean;
  const float rstd = rsqrtf(var + 1e-5f);
  const float4 gv = *(const float4*)(g + t * 4);
  const float4 bv = *(const float4*)(bta + t * 4);
  union { unsigned short u[4]; uint2 p; } o;
  o.u[0] = f2bf((v.x - mean) * rstd * gv.x + bv.x);
  o.u[1] = f2bf((v.y - mean) * rstd * gv.y + bv.y);
  o.u[2] = f2bf((v.z - mean) * rstd * gv.z + bv.z);
  o.u[3] = f2bf((v.w - mean) * rstd * gv.w + bv.w);
  *(uint2*)(out + (size_t)row * 1024 + t * 4) = o.p;
}

// ---------------------------------------------------------------------------
// fold + LayerNorm fused. s = x + outb + P0 + P1 (out-proj result), then
// ln2(s) -> xm (bf16) and d_out = s + b2 (fp32, seeds MLP-down).
// ---------------------------------------------------------------------------
__global__ __launch_bounds__(256) void fold_ln(
    const float* __restrict__ x,
    const float* __restrict__ P0,
    const float* __restrict__ P1,
    const float* __restrict__ ob_bias,
    const float* __restrict__ g,
    const float* __restrict__ bta,
    unsigned short* __restrict__ out,      // xm (bf16)
    const float* __restrict__ seed_bias,   // b2
    float* __restrict__ seed_out) {        // d_out (fp32)
  const int row = blockIdx.x, t = threadIdx.x;
  const size_t off = (size_t)row * 1024 + t * 4;
  float4 v = *(const float4*)(x + off);
  const float4 p0 = *(const float4*)(P0 + off);
  const float4 p1 = *(const float4*)(P1 + off);
  const float4 ob = *(const float4*)(ob_bias + t * 4);
  v.x += p0.x + p1.x + ob.x;
  v.y += p0.y + p1.y + ob.y;
  v.z += p0.z + p1.z + ob.z;
  v.w += p0.w + p1.w + ob.w;
  {
    float4 sb = *(const float4*)(seed_bias + t * 4);
    float4 sv;
    sv.x = v.x + sb.x; sv.y = v.y + sb.y; sv.z = v.z + sb.z; sv.w = v.w + sb.w;
    *(float4*)(seed_out + off) = sv;
  }
  float s1 = v.x + v.y + v.z + v.w;
  float s2 = v.x*v.x + v.y*v.y + v.z*v.z + v.w*v.w;
  #pragma unroll
  for (int o2 = 1; o2 < 64; o2 <<= 1) {
    s1 += __shfl_xor(s1, o2, 64);
    s2 += __shfl_xor(s2, o2, 64);
  }
  __shared__ float r1[4], r2[4];
  if ((t & 63) == 0) { r1[t >> 6] = s1; r2[t >> 6] = s2; }
  __syncthreads();
  s1 = r1[0] + r1[1] + r1[2] + r1[3];
  s2 = r2[0] + r2[1] + r2[2] + r2[3];
  const float mean = s1 * (1.0f / 1024.0f);
  const float var  = s2 * (1.0f / 1024.0f) - mean * mean;
  const float rstd = rsqrtf(var + 1e-5f);
  const float4 gv = *(const float4*)(g + t * 4);
  const float4 bv = *(const float4*)(bta + t * 4);
  union { unsigned short u[4]; uint2 p; } o;
  o.u[0] = f2bf((v.x - mean) * rstd * gv.x + bv.x);
  o.u[1] = f2bf((v.y - mean) * rstd * gv.y + bv.y);
  o.u[2] = f2bf((v.z - mean) * rstd * gv.z + bv.z);
  o.u[3] = f2bf((v.w - mean) * rstd * gv.w + bv.w);
  *(uint2*)(out + off) = o.p;
}

// ---------------------------------------------------------------------------
// Pipelined GEMM core (R0 double-buffered skeleton). R10: SWZ template flag.
// SWZ=1: XCD-chunked + 8x8-patch swizzle (R9 — won on QKV/out-proj/down).
// SWZ=0: linear R8 mapping (won on MLP-up: R9 A/B showed patch swizzle cost
// it 42.0->45.0 us while FETCH dropped — over-fetch was cost-free there).
// bid/nwg passed explicitly so mixed-grid kernels (qkv_cvt) can call in.
// MODE 0 = bf16 v+bias; MODE 2 = bf16 relu(v+bias); MODE 5 = fp32 partials.
// ---------------------------------------------------------------------------
template <int MODE, int SWZ>
__device__ __forceinline__ void gemm_core(
    const unsigned short* __restrict__ A,
    const unsigned short* __restrict__ Bt,
    const float* __restrict__ bias,
    void* __restrict__ outp,
    int N, int K, int kbeg, int kend,
    unsigned short* As, unsigned short* Bs,
    int bid, int nwg) {
  const int tid = threadIdx.x;
  const int wave = tid >> 6, lane = tid & 63;
  const int q = lane >> 4, c = lane & 15;
  const int wm = (wave & 1) << 6, wn = (wave >> 1) << 6;

  int m0, n0;
  if (SWZ) {
    const int v_ = (bid & 7) * (nwg >> 3) + (bid >> 3);
    const int patch = v_ >> 6, u_ = v_ & 63;
    m0 = (((patch & 3) << 3) + (u_ & 7)) << 7;
    n0 = (((patch >> 2) << 3) + (u_ >> 3)) << 7;
  } else {
    m0 = (bid & 31) << 7;
    n0 = (bid >> 5) << 7;
  }

  const int srow = tid >> 3;                       // 0..31
  const int cg8  = ((tid & 7) ^ (srow & 7)) << 3;  // swizzled col chunk

  const unsigned short* gA = A  + (size_t)(m0 + srow) * K + cg8;
  const unsigned short* gB = Bt + (size_t)(n0 + srow) * K + cg8;
  const size_t rstep = (size_t)32 * K;

  auto issue = [&](int k0, int buf) {
    unsigned short* lA = As + buf * 8192 + tid * 8;
    unsigned short* lB = Bs + buf * 8192 + tid * 8;
    #pragma unroll
    for (int it = 0; it < 4; it++) {
      cp16(gA + it * rstep + k0, lA + it * 2048);
      cp16(gB + it * rstep + k0, lB + it * 2048);
    }
  };

  const f32x4 fzero = {0.f, 0.f, 0.f, 0.f};
  f32x4 acc[4][4];
  #pragma unroll
  for (int i = 0; i < 4; i++)
    #pragma unroll
    for (int j = 0; j < 4; j++) acc[i][j] = fzero;

  issue(kbeg, 0);
  if (kbeg + 64 < kend) issue(kbeg + 64, 1);

  int buf = 0;
  for (int k0 = kbeg; k0 < kend; k0 += 64, buf ^= 1) {
    if (k0 + 64 < kend) asm volatile("s_waitcnt vmcnt(8)" ::: "memory");
    else                asm volatile("s_waitcnt vmcnt(0)" ::: "memory");
    asm volatile("s_barrier" ::: "memory");

    const unsigned short* cA = As + buf * 8192;
    const unsigned short* cB = Bs + buf * 8192;
    #pragma unroll
    for (int ks = 0; ks < 2; ks++) {
      const int sw = (((ks << 2) + q) ^ (c & 7)) << 3;
      bf16x8 af[4], bf[4];
      #pragma unroll
      for (int i = 0; i < 4; i++) af[i] = *(const bf16x8*)&cA[(wm + i*16 + c)*64 + sw];
      #pragma unroll
      for (int j = 0; j < 4; j++) bf[j] = *(const bf16x8*)&cB[(wn + j*16 + c)*64 + sw];
      #pragma unroll
      for (int i = 0; i < 4; i++)
        #pragma unroll
        for (int j = 0; j < 4; j++)
          acc[i][j] = __builtin_amdgcn_mfma_f32_16x16x32_bf16(af[i], bf[j], acc[i][j], 0, 0, 0);
    }

    asm volatile("s_barrier" ::: "memory");
    if (k0 + 128 < kend) issue(k0 + 128, buf);
  }

  if (MODE == 5) {
    float* op = (float*)outp;
    #pragma unroll
    for (int i = 0; i < 4; i++) {
      #pragma unroll
      for (int r = 0; r < 4; r++) {
        const int row = m0 + wm + i * 16 + q * 4 + r;
        #pragma unroll
        for (int j = 0; j < 4; j++) {
          const int col = n0 + wn + j * 16 + c;
          op[(size_t)row * N + col] = acc[i][j][r];
        }
      }
    }
  } else {
    float bj[4];
    #pragma unroll
    for (int j = 0; j < 4; j++) bj[j] = bias[n0 + wn + j * 16 + c];
    #pragma unroll
    for (int i = 0; i < 4; i++) {
      #pragma unroll
      for (int r = 0; r < 4; r++) {
        const int row = m0 + wm + i * 16 + q * 4 + r;
        #pragma unroll
        for (int j = 0; j < 4; j++) {
          const int col = n0 + wn + j * 16 + c;
          const size_t idx = (size_t)row * N + col;
          float v = acc[i][j][r] + bj[j];
          if (MODE == 0) ((unsigned short*)outp)[idx] = f2bf(v);
          else           ((unsigned short*)outp)[idx] = f2bf(fmaxf(v, 0.f));
        }
      }
    }
  }
}

template <int MODE, int SWZ>
__global__ __launch_bounds__(256, 2) void gemm_bt(
    const unsigned short* __restrict__ A,
    const unsigned short* __restrict__ Bt,
    const float* __restrict__ bias,
    void* __restrict__ outp,
    int N, int K) {
  __shared__ __align__(16) unsigned short As[2 * 8192];
  __shared__ __align__(16) unsigned short Bs[2 * 8192];
  gemm_core<MODE, SWZ>(A, Bt, bias, outp, N, K, 0, K, As, Bs,
                       blockIdx.x + (blockIdx.y << 5), gridDim.x * gridDim.y);
}

// ---------------------------------------------------------------------------
// R10: QKV GEMM (blocks 0..767, swizzled) + outw/w1/w2 fp32->bf16 converts
// (blocks 768..9983) in ONE launch. Convert blocks backfill the GEMM's
// drain tail / idle slots — overlapped instead of serial in cvt_ln1.
// Converts write buffers consumed only 3+ launches later (no ordering risk).
// ---------------------------------------------------------------------------
__global__ __launch_bounds__(256, 2) void qkv_cvt(
    const unsigned short* __restrict__ A,
    const unsigned short* __restrict__ Bt,
    const float* __restrict__ bias,
    unsigned short* __restrict__ outp,
    const float* __restrict__ cw0, unsigned short* __restrict__ cd0,   // outw 1024 blk
    const float* __restrict__ cw1, unsigned short* __restrict__ cd1,   // w1   4096 blk
    const float* __restrict__ cw2, unsigned short* __restrict__ cd2) { // w2   4096 blk
  if (blockIdx.x >= 768) {
    int b = blockIdx.x - 768;
    const float* src; unsigned short* dst;
    if (b < 1024)      { src = cw0; dst = cd0; }
    else if (b < 5120) { src = cw1; dst = cd1; b -= 1024; }
    else               { src = cw2; dst = cd2; b -= 5120; }
    cvt4(src, dst, (b * 256 + threadIdx.x) * 4);
    return;
  }
  __shared__ __align__(16) unsigned short As[2 * 8192];
  __shared__ __align__(16) unsigned short Bs[2 * 8192];
  gemm_core<0, 1>(A, Bt, bias, outp, 3072, 1024, 0, 1024, As, Bs,
                  blockIdx.x, 768);
}

// split-K=2 WITHOUT atomics: z writes its partial to Qz with plain stores.
__global__ __launch_bounds__(256, 2) void gemm_bt_splitk_p(
    const unsigned short* __restrict__ A,
    const unsigned short* __restrict__ Bt,
    float* __restrict__ Q0,
    float* __restrict__ Q1,
    int N, int K) {
  __shared__ __align__(16) unsigned short As[2 * 8192];
  __shared__ __align__(16) unsigned short Bs[2 * 8192];
  const int KH = K >> 1;
  const int kbeg = blockIdx.z * KH;
  gemm_core<5, 1>(A, Bt, nullptr, blockIdx.z ? Q1 : Q0, N, K, kbeg, kbeg + KH,
                  As, Bs, blockIdx.x + (blockIdx.y << 5), gridDim.x * gridDim.y);
}

// d_out += Q0 + Q1 (fp32, 4096x1024). 2048 blocks x 256 thr x f32x4 x 2 iter.
__global__ __launch_bounds__(256) void fold2(
    const float* __restrict__ Q0,
    const float* __restrict__ Q1,
    float* __restrict__ out) {
  int i = (blockIdx.x * 256 + threadIdx.x) * 4;
  #pragma unroll
  for (int it = 0; it < 2; it++) {
    float4 a  = *(const float4*)(out + i);
    float4 q0 = *(const float4*)(Q0 + i);
    float4 q1 = *(const float4*)(Q1 + i);
    a.x += q0.x + q1.x; a.y += q0.y + q1.y;
    a.z += q0.z + q1.z; a.w += q0.w + q1.w;
    *(float4*)(out + i) = a;
    i += 2097152;
  }
}

// ---------------------------------------------------------------------------
// Flash attention, causal + rel_pos bias. K/V double-buffered (R6/R7).
// R10: s_setprio(1) around MFMA clusters (T5; m191 +4-7% on attn with
// independent blocks — ours has 2 independent blocks/CU).
// ---------------------------------------------------------------------------
__global__ __launch_bounds__(256, 2) void attn_flash(
    const unsigned short* __restrict__ qkv,   // [4096, 3072] bf16 (q|k|v)
    const float* __restrict__ rel_pos,        // [16, 2048] fp32
    unsigned short* __restrict__ o) {         // [4096, 1024] bf16 ([b,s,h,d])
  __shared__ __align__(16) unsigned short Qs[128 * 64];
  __shared__ __align__(16) unsigned short Ks[2][64 * 64];
  __shared__ __align__(16) unsigned short Vs[2][64 * 64];  // transposed [d][kt]
  __shared__ __align__(16) unsigned short Ps[4][32 * 64];
  __shared__ float rps[1024];                              // rel_pos[h,:]*log2e

  const int tid = threadIdx.x;
  const int wave = tid >> 6, lane = tid & 63;
  const int q = lane >> 4, c = lane & 15;

  const int lid = blockIdx.x + (blockIdx.y << 3);
  const int xq = lid & 7, y = lid >> 3;
  const int qt = (y & 32) ? (7 - xq) : xq;
  const int b = y >> 4, h = y & 15;

  const unsigned short* qg = qkv + (size_t)b * 1024 * 3072 + h * 64;
  const unsigned short* kg = qg + 1024;
  const unsigned short* vg = qg + 2048;

  #pragma unroll
  for (int i = 0; i < 4; i++) {
    const int idx = tid + i * 256;
    rps[idx & 1023] = rel_pos[h * 2048 + (idx & 1023)] * 1.44269504f;
  }

  const int sr  = tid >> 3;
  const int cg8 = ((tid & 7) ^ (sr & 7)) << 3;
  #pragma unroll
  for (int it = 0; it < 4; it++)
    cp16(qg + (size_t)(qt * 128 + sr + it * 32) * 3072 + cg8, &Qs[(tid + it * 256) * 8]);

  const int vrow = tid & 63, d0 = (tid >> 6) << 4;
  const int vchunk = vrow >> 3, vlo = vrow & 7;

  // prologue: issue K(0)->Ks[0], V(0)->regs (drained by first barrier)
  cp16(kg + (size_t)sr * 3072 + cg8, &Ks[0][tid * 8]);
  cp16(kg + (size_t)(sr + 32) * 3072 + cg8, &Ks[0][(tid + 256) * 8]);
  union { int4 v; unsigned short u[8]; } va, vb2;
  {
    const unsigned short* vrp = vg + (size_t)vrow * 3072 + d0;
    va.v  = *(const int4*)vrp;
    vb2.v = *(const int4*)(vrp + 8);
  }
  __syncthreads();

  bf16x8 qf[2][2];
  #pragma unroll
  for (int mt = 0; mt < 2; mt++)
    #pragma unroll
    for (int ks = 0; ks < 2; ks++)
      qf[mt][ks] = *(const bf16x8*)&Qs[(wave*32 + mt*16 + c)*64 + ((((ks<<2)+q) ^ (c & 7)) << 3)];

  const f32x4 fzero = {0.f, 0.f, 0.f, 0.f};
  f32x4 O[2][4];
  float l_i[2][4];
  #pragma unroll
  for (int mt = 0; mt < 2; mt++) {
    #pragma unroll
    for (int r = 0; r < 4; r++) l_i[mt][r] = 0.f;
    #pragma unroll
    for (int dt = 0; dt < 4; dt++) O[mt][dt] = fzero;
  }

  unsigned short* Pw = &Ps[wave][0];
  const int i_base = qt * 128 + wave * 32;

  const float sc = 0.125f * 1.44269504f;
  const int kdiag = qt << 1;
  const int nkt = (qt + 1) * 2;

  for (int kt = 0; kt < nkt; kt++) {
    const int buf = kt & 1;

    // 1. all of tile kt's loads have landed (K in LDS, V in regs)
    asm volatile("s_waitcnt vmcnt(0)" ::: "memory");

    // 2. write V(kt) regs -> Vs[buf] (swizzled transpose)
    #pragma unroll
    for (int j = 0; j < 8; j++) {
      const int pos = ((vchunk ^ j) << 3) + vlo;
      Vs[buf][(d0 + j) * 64 + pos]     = va.u[j];
      Vs[buf][(d0 + 8 + j) * 64 + pos] = vb2.u[j];
    }

    // 3. barrier: V writes visible; all waves done reading buf^1
    __syncthreads();

    // 4. prefetch tile kt+1 into buf^1 / regs
    if (kt + 1 < nkt) {
      cp16(kg + (size_t)((kt + 1) * 64 + sr) * 3072 + cg8, &Ks[buf ^ 1][tid * 8]);
      cp16(kg + (size_t)((kt + 1) * 64 + sr + 32) * 3072 + cg8, &Ks[buf ^ 1][(tid + 256) * 8]);
      const unsigned short* vrp = vg + (size_t)((kt + 1) * 64 + vrow) * 3072 + d0;
      va.v  = *(const int4*)vrp;
      vb2.v = *(const int4*)(vrp + 8);
    }

    // 5. compute on buf
    f32x4 S[2][4];
    #pragma unroll
    for (int mt = 0; mt < 2; mt++)
      #pragma unroll
      for (int nt = 0; nt < 4; nt++) S[mt][nt] = fzero;
    __builtin_amdgcn_s_setprio(1);
    #pragma unroll
    for (int ks = 0; ks < 2; ks++) {
      const int sw = (((ks << 2) + q) ^ (c & 7)) << 3;
      bf16x8 kb[4];
      #pragma unroll
      for (int nt = 0; nt < 4; nt++) kb[nt] = *(const bf16x8*)&Ks[buf][(nt*16 + c)*64 + sw];
      #pragma unroll
      for (int mt = 0; mt < 2; mt++)
        #pragma unroll
        for (int nt = 0; nt < 4; nt++)
          S[mt][nt] = __builtin_amdgcn_mfma_f32_16x16x32_bf16(qf[mt][ks], kb[nt], S[mt][nt], 0, 0, 0);
    }
    __builtin_amdgcn_s_setprio(0);

    if (kt < kdiag) {
      #pragma unroll
      for (int mt = 0; mt < 2; mt++) {
        #pragma unroll
        for (int r = 0; r < 4; r++) {
          const int i_ = i_base + mt * 16 + q * 4 + r;
          const int prow = (mt * 16 + q * 4 + r) * 64;
          const int rsw  = (q * 4 + r) & 7;
          float s = 0.f;
          #pragma unroll
          for (int nt = 0; nt < 4; nt++) {
            const int j_ = kt * 64 + nt * 16 + c;
            const float p = exp2f(fmaf(S[mt][nt][r], sc, rps[i_ - j_]));
            s += p;
            Pw[prow + ((((nt << 1) + (c >> 3)) ^ rsw) << 3) + (c & 7)] = f2bf_fast(p);
          }
          l_i[mt][r] += s;
        }
      }
    } else {
      #pragma unroll
      for (int mt = 0; mt < 2; mt++) {
        #pragma unroll
        for (int r = 0; r < 4; r++) {
          const int i_ = i_base + mt * 16 + q * 4 + r;
          const int prow = (mt * 16 + q * 4 + r) * 64;
          const int rsw  = (q * 4 + r) & 7;
          float s = 0.f;
          #pragma unroll
          for (int nt = 0; nt < 4; nt++) {
            const int j_ = kt * 64 + nt * 16 + c;
            const int d_ = i_ - j_;
            const float p = (d_ >= 0)
                ? exp2f(fmaf(S[mt][nt][r], sc, rps[d_ & 1023])) : 0.f;
            s += p;
            Pw[prow + ((((nt << 1) + (c >> 3)) ^ rsw) << 3) + (c & 7)] = f2bf_fast(p);
          }
          l_i[mt][r] += s;
        }
      }
    }

    asm volatile("s_waitcnt lgkmcnt(0)" ::: "memory");

    __builtin_amdgcn_s_setprio(1);
    #pragma unroll
    for (int ks = 0; ks < 2; ks++) {
      const int sw = (((ks << 2) + q) ^ (c & 7)) << 3;
      bf16x8 pa[2], vb[4];
      #pragma unroll
      for (int mt = 0; mt < 2; mt++) pa[mt] = *(const bf16x8*)&Pw[(mt*16 + c)*64 + sw];
      #pragma unroll
      for (int dt = 0; dt < 4; dt++) vb[dt] = *(const bf16x8*)&Vs[buf][(dt*16 + c)*64 + sw];
      #pragma unroll
      for (int mt = 0; mt < 2; mt++)
        #pragma unroll
        for (int dt = 0; dt < 4; dt++)
          O[mt][dt] = __builtin_amdgcn_mfma_f32_16x16x32_bf16(pa[mt], vb[dt], O[mt][dt], 0, 0, 0);
    }
    __builtin_amdgcn_s_setprio(0);
  }

  #pragma unroll
  for (int mt = 0; mt < 2; mt++) {
    #pragma unroll
    for (int r = 0; r < 4; r++) {
      float l = l_i[mt][r];
      l += __shfl_xor(l, 1, 64);
      l += __shfl_xor(l, 2, 64);
      l += __shfl_xor(l, 4, 64);
      l += __shfl_xor(l, 8, 64);
      const float inv = 1.0f / l;
      const int i_ = i_base + mt * 16 + q * 4 + r;
      unsigned short* orow = o + (size_t)(b * 1024 + i_) * 1024 + h * 64 + c;
      #pragma unroll
      for (int dt = 0; dt < 4; dt++) orow[dt * 16] = f2bf(O[mt][dt][r] * inv);
    }
  }
}

// ---------------------------------------------------------------------------
// Launch. Workspace ~81 MB, aliased.
// Out-proj partials: P0 = qkvb head (qkv dead after attn), P1 = x2 scratch.
// MLP-down partials: Q0 = [ipw_b..w1_b] (dead), Q1 = x2 (dead after fold_ln).
// ---------------------------------------------------------------------------
extern "C" void kernel_launch(void* const* d_in, const int* in_sizes, int n_in,
                              void* d_out, int out_size, void* d_ws, size_t ws_size,
                              hipStream_t stream) {
  (void)in_sizes; (void)n_in; (void)out_size; (void)ws_size;
  const float* x    = (const float*)d_in[0];
  const float* rel  = (const float*)d_in[1];
  const float* ipw  = (const float*)d_in[2];
  const float* ipb  = (const float*)d_in[3];
  const float* outw = (const float*)d_in[4];
  const float* outb = (const float*)d_in[5];
  const float* w1   = (const float*)d_in[6];
  const float* b1   = (const float*)d_in[7];
  const float* w2   = (const float*)d_in[8];
  const float* b2   = (const float*)d_in[9];
  const float* ln1g = (const float*)d_in[10];
  const float* ln1b = (const float*)d_in[11];
  const float* ln2g = (const float*)d_in[12];
  const float* ln2b = (const float*)d_in[13];

  // workspace layout (elements), aliased:
  unsigned short* ipw_b  = (unsigned short*)d_ws;            // 3072*1024
  unsigned short* outw_b = ipw_b  + (size_t)3072 * 1024;     // 1024*1024
  unsigned short* w1_b   = outw_b + (size_t)1024 * 1024;     // 4096*1024
  unsigned short* w2_b   = w1_b   + (size_t)4096 * 1024;     // 1024*4096
  unsigned short* xn     = w2_b   + (size_t)1024 * 4096;     // 4096*1024 (also xm)
  unsigned short* qkvb   = xn     + (size_t)4096 * 1024;     // 4096*3072 ┐
  unsigned short* ob     = qkvb   + (size_t)4096 * 3072;     // 4096*1024 ┴ hb aliases both
  unsigned short* hb     = qkvb;                             // 4096*4096 (after fold_ln)
  unsigned short* xm     = xn;                               // after QKV consumed xn
  float*          x2     = (float*)(ob + (size_t)4096 * 1024);  // 4096*1024 f32 scratch
  // out-proj partials (dead regions at out-proj launch):
  float*          P0     = (float*)qkvb;   // qkv dead after attn; ob untouched
  float*          P1     = x2;
  // MLP-down partials (dead regions at down launch):
  float*          Q0     = (float*)d_ws;   // ipw_b+outw_b+w1_b = 16.78 MB
  float*          Q1     = x2;
  // total = 81 MB

  // ipw convert + ln1 (only what QKV needs immediately)
  cvt_ln1<<<7168, 256, 0, stream>>>(ipw, ipw_b, x, ln1g, ln1b, xn);

  // QKV proj (768 swizzled GEMM blocks) + outw/w1/w2 converts (9216 blocks,
  // backfill the GEMM drain tail)
  qkv_cvt<<<9984, 256, 0, stream>>>(xn, ipw_b, ipb, qkvb,
                                    outw, outw_b, w1, w1_b, w2, w2_b);

  attn_flash<<<dim3(8, 64), 256, 0, stream>>>(qkvb, rel, ob);

  // attn out proj: partials P0/P1 (split-K=2, no atomics, swizzled)
  gemm_bt_splitk_p<<<dim3(32, 8, 2), 256, 0, stream>>>(ob, outw_b, P0, P1, 1024, 1024);

  // fold + ln2 + seed: x2 = x + outb + P0 + P1; xm = ln2(x2); d_out = x2 + b2
  fold_ln<<<4096, 256, 0, stream>>>(x, P0, P1, outb, ln2g, ln2b, xm, b2, (float*)d_out);

  // MLP up (linear mapping — R9 A/B showed patch swizzle cost it 3us)
  gemm_bt<2, 0><<<dim3(32, 32), 256, 0, stream>>>(xm, w1_b, b1, hb, 4096, 1024);

  // MLP down, atomic-free: partials Q0/Q1, then d_out += Q0 + Q1
  gemm_bt_splitk_p<<<dim3(32, 8, 2), 256, 0, stream>>>(hb, w2_b, Q0, Q1, 1024, 4096);
  fold2<<<2048, 256, 0, stream>>>(Q0, Q1, (float*)d_out);
}

// Round 11
// 299.270 us; speedup vs baseline: 1.0526x; 1.0526x over previous
//
#include <hip/hip_runtime.h>
#include <stdint.h>

// ---------------------------------------------------------------------------
// Types / helpers
// ---------------------------------------------------------------------------
typedef __bf16 bf16x8 __attribute__((ext_vector_type(8)));
typedef float  f32x4  __attribute__((ext_vector_type(4)));

__device__ __forceinline__ unsigned short f2bf(float f) {
  union { float f; unsigned int u; } a; a.f = f;
  unsigned int r = a.u + 0x7FFFu + ((a.u >> 16) & 1u);   // RNE
  return (unsigned short)(r >> 16);
}

__device__ __forceinline__ unsigned short f2bf_fast(float f) {
  union { __bf16 b; unsigned short u; } v; v.b = (__bf16)f; return v.u;
}

// async global->LDS, 16B per lane. LDS dest must be wave-uniform base + lane*16.
__device__ __forceinline__ void cp16(const void* g, void* l) {
  auto g1 = reinterpret_cast<__attribute__((address_space(1))) unsigned int*>(
      reinterpret_cast<uintptr_t>(g));
  auto l3 = reinterpret_cast<__attribute__((address_space(3))) unsigned int*>(
      reinterpret_cast<uintptr_t>(l));
  __builtin_amdgcn_global_load_lds(g1, l3, 16, 0, 0);
}

// ---------------------------------------------------------------------------
// Fused: weight fp32->bf16 convert (blocks 0..12287) AND ln1 (blocks
// 12288..16383). R11: reverted to the R9 serial-convert form — R10's
// fusion of converts into the QKV launch co-scheduled converts WITH the
// GEMM blocks (2/CU occupancy), stealing BW from the critical path
// (qkv_cvt 48.6us vs 34+overlap predicted).
// ---------------------------------------------------------------------------
__global__ __launch_bounds__(256) void cvt_ln1(
    const float* __restrict__ s0, const float* __restrict__ s1,
    const float* __restrict__ s2, const float* __restrict__ s3,
    unsigned short* __restrict__ d0, unsigned short* __restrict__ d1,
    unsigned short* __restrict__ d2, unsigned short* __restrict__ d3,
    const float* __restrict__ x,
    const float* __restrict__ g,
    const float* __restrict__ bta,
    unsigned short* __restrict__ out) {
  if (blockIdx.x < 12288) {
    int i = (blockIdx.x * 256 + threadIdx.x) * 4;
    const float* src; unsigned short* dst; int off;
    if (i < 3145728)       { src = s0; dst = d0; off = 0; }
    else if (i < 4194304)  { src = s1; dst = d1; off = 3145728; }
    else if (i < 8388608)  { src = s2; dst = d2; off = 4194304; }
    else                   { src = s3; dst = d3; off = 8388608; }
    i -= off;
    float4 v = *(const float4*)(src + i);
    union { unsigned short u[4]; uint2 p; } o;
    o.u[0] = f2bf(v.x); o.u[1] = f2bf(v.y); o.u[2] = f2bf(v.z); o.u[3] = f2bf(v.w);
    *(uint2*)(dst + i) = o.p;
    return;
  }
  const int row = blockIdx.x - 12288, t = threadIdx.x;
  const float4 v = *(const float4*)(x + (size_t)row * 1024 + t * 4);
  float s1v = v.x + v.y + v.z + v.w;
  float s2v = v.x*v.x + v.y*v.y + v.z*v.z + v.w*v.w;
  #pragma unroll
  for (int off = 1; off < 64; off <<= 1) {
    s1v += __shfl_xor(s1v, off, 64);
    s2v += __shfl_xor(s2v, off, 64);
  }
  __shared__ float r1[4], r2[4];
  if ((t & 63) == 0) { r1[t >> 6] = s1v; r2[t >> 6] = s2v; }
  __syncthreads();
  s1v = r1[0] + r1[1] + r1[2] + r1[3];
  s2v = r2[0] + r2[1] + r2[2] + r2[3];
  const float mean = s1v * (1.0f / 1024.0f);
  const float var  = s2v * (1.0f / 1024.0f) - mean * mean;
  const float rstd = rsqrtf(var + 1e-5f);
  const float4 gv = *(const float4*)(g + t * 4);
  const float4 bv = *(const float4*)(bta + t * 4);
  union { unsigned short u[4]; uint2 p; } o;
  o.u[0] = f2bf((v.x - mean) * rstd * gv.x + bv.x);
  o.u[1] = f2bf((v.y - mean) * rstd * gv.y + bv.y);
  o.u[2] = f2bf((v.z - mean) * rstd * gv.z + bv.z);
  o.u[3] = f2bf((v.w - mean) * rstd * gv.w + bv.w);
  *(uint2*)(out + (size_t)row * 1024 + t * 4) = o.p;
}

// ---------------------------------------------------------------------------
// fold + LayerNorm fused. s = x + outb + P0 + P1 (out-proj result), then
// ln2(s) -> xm (bf16) and d_out = s + b2 (fp32, seeds MLP-down).
// ---------------------------------------------------------------------------
__global__ __launch_bounds__(256) void fold_ln(
    const float* __restrict__ x,
    const float* __restrict__ P0,
    const float* __restrict__ P1,
    const float* __restrict__ ob_bias,
    const float* __restrict__ g,
    const float* __restrict__ bta,
    unsigned short* __restrict__ out,      // xm (bf16)
    const float* __restrict__ seed_bias,   // b2
    float* __restrict__ seed_out) {        // d_out (fp32)
  const int row = blockIdx.x, t = threadIdx.x;
  const size_t off = (size_t)row * 1024 + t * 4;
  float4 v = *(const float4*)(x + off);
  const float4 p0 = *(const float4*)(P0 + off);
  const float4 p1 = *(const float4*)(P1 + off);
  const float4 ob = *(const float4*)(ob_bias + t * 4);
  v.x += p0.x + p1.x + ob.x;
  v.y += p0.y + p1.y + ob.y;
  v.z += p0.z + p1.z + ob.z;
  v.w += p0.w + p1.w + ob.w;
  {
    float4 sb = *(const float4*)(seed_bias + t * 4);
    float4 sv;
    sv.x = v.x + sb.x; sv.y = v.y + sb.y; sv.z = v.z + sb.z; sv.w = v.w + sb.w;
    *(float4*)(seed_out + off) = sv;
  }
  float s1 = v.x + v.y + v.z + v.w;
  float s2 = v.x*v.x + v.y*v.y + v.z*v.z + v.w*v.w;
  #pragma unroll
  for (int o2 = 1; o2 < 64; o2 <<= 1) {
    s1 += __shfl_xor(s1, o2, 64);
    s2 += __shfl_xor(s2, o2, 64);
  }
  __shared__ float r1[4], r2[4];
  if ((t & 63) == 0) { r1[t >> 6] = s1; r2[t >> 6] = s2; }
  __syncthreads();
  s1 = r1[0] + r1[1] + r1[2] + r1[3];
  s2 = r2[0] + r2[1] + r2[2] + r2[3];
  const float mean = s1 * (1.0f / 1024.0f);
  const float var  = s2 * (1.0f / 1024.0f) - mean * mean;
  const float rstd = rsqrtf(var + 1e-5f);
  const float4 gv = *(const float4*)(g + t * 4);
  const float4 bv = *(const float4*)(bta + t * 4);
  union { unsigned short u[4]; uint2 p; } o;
  o.u[0] = f2bf((v.x - mean) * rstd * gv.x + bv.x);
  o.u[1] = f2bf((v.y - mean) * rstd * gv.y + bv.y);
  o.u[2] = f2bf((v.z - mean) * rstd * gv.z + bv.z);
  o.u[3] = f2bf((v.w - mean) * rstd * gv.w + bv.w);
  *(uint2*)(out + off) = o.p;
}

// ---------------------------------------------------------------------------
// Pipelined GEMM core (R0 double-buffered skeleton). SWZ template flag:
// SWZ=1: XCD-chunked + 8x8-patch swizzle — won on QKV/out-proj/MLP-down
//        (R9: collectively −5.6us, FETCH −19%).
// SWZ=0: linear mapping — won on MLP-up (R9 A/B: swizzle cost 42.0->45.0us;
//        its over-fetch is cost-free at 18% HBM).
// MODE 0 = bf16 v+bias; MODE 2 = bf16 relu(v+bias); MODE 5 = fp32 partials.
// ---------------------------------------------------------------------------
template <int MODE, int SWZ>
__device__ __forceinline__ void gemm_core(
    const unsigned short* __restrict__ A,
    const unsigned short* __restrict__ Bt,
    const float* __restrict__ bias,
    void* __restrict__ outp,
    int N, int K, int kbeg, int kend,
    unsigned short* As, unsigned short* Bs,
    int bid, int nwg) {
  const int tid = threadIdx.x;
  const int wave = tid >> 6, lane = tid & 63;
  const int q = lane >> 4, c = lane & 15;
  const int wm = (wave & 1) << 6, wn = (wave >> 1) << 6;

  int m0, n0;
  if (SWZ) {
    const int v_ = (bid & 7) * (nwg >> 3) + (bid >> 3);
    const int patch = v_ >> 6, u_ = v_ & 63;
    m0 = (((patch & 3) << 3) + (u_ & 7)) << 7;
    n0 = (((patch >> 2) << 3) + (u_ >> 3)) << 7;
  } else {
    m0 = (bid & 31) << 7;
    n0 = (bid >> 5) << 7;
  }

  const int srow = tid >> 3;                       // 0..31
  const int cg8  = ((tid & 7) ^ (srow & 7)) << 3;  // swizzled col chunk

  const unsigned short* gA = A  + (size_t)(m0 + srow) * K + cg8;
  const unsigned short* gB = Bt + (size_t)(n0 + srow) * K + cg8;
  const size_t rstep = (size_t)32 * K;

  auto issue = [&](int k0, int buf) {
    unsigned short* lA = As + buf * 8192 + tid * 8;
    unsigned short* lB = Bs + buf * 8192 + tid * 8;
    #pragma unroll
    for (int it = 0; it < 4; it++) {
      cp16(gA + it * rstep + k0, lA + it * 2048);
      cp16(gB + it * rstep + k0, lB + it * 2048);
    }
  };

  const f32x4 fzero = {0.f, 0.f, 0.f, 0.f};
  f32x4 acc[4][4];
  #pragma unroll
  for (int i = 0; i < 4; i++)
    #pragma unroll
    for (int j = 0; j < 4; j++) acc[i][j] = fzero;

  issue(kbeg, 0);
  if (kbeg + 64 < kend) issue(kbeg + 64, 1);

  int buf = 0;
  for (int k0 = kbeg; k0 < kend; k0 += 64, buf ^= 1) {
    if (k0 + 64 < kend) asm volatile("s_waitcnt vmcnt(8)" ::: "memory");
    else                asm volatile("s_waitcnt vmcnt(0)" ::: "memory");
    asm volatile("s_barrier" ::: "memory");

    const unsigned short* cA = As + buf * 8192;
    const unsigned short* cB = Bs + buf * 8192;
    #pragma unroll
    for (int ks = 0; ks < 2; ks++) {
      const int sw = (((ks << 2) + q) ^ (c & 7)) << 3;
      bf16x8 af[4], bf[4];
      #pragma unroll
      for (int i = 0; i < 4; i++) af[i] = *(const bf16x8*)&cA[(wm + i*16 + c)*64 + sw];
      #pragma unroll
      for (int j = 0; j < 4; j++) bf[j] = *(const bf16x8*)&cB[(wn + j*16 + c)*64 + sw];
      #pragma unroll
      for (int i = 0; i < 4; i++)
        #pragma unroll
        for (int j = 0; j < 4; j++)
          acc[i][j] = __builtin_amdgcn_mfma_f32_16x16x32_bf16(af[i], bf[j], acc[i][j], 0, 0, 0);
    }

    asm volatile("s_barrier" ::: "memory");
    if (k0 + 128 < kend) issue(k0 + 128, buf);
  }

  if (MODE == 5) {
    float* op = (float*)outp;
    #pragma unroll
    for (int i = 0; i < 4; i++) {
      #pragma unroll
      for (int r = 0; r < 4; r++) {
        const int row = m0 + wm + i * 16 + q * 4 + r;
        #pragma unroll
        for (int j = 0; j < 4; j++) {
          const int col = n0 + wn + j * 16 + c;
          op[(size_t)row * N + col] = acc[i][j][r];
        }
      }
    }
  } else {
    float bj[4];
    #pragma unroll
    for (int j = 0; j < 4; j++) bj[j] = bias[n0 + wn + j * 16 + c];
    #pragma unroll
    for (int i = 0; i < 4; i++) {
      #pragma unroll
      for (int r = 0; r < 4; r++) {
        const int row = m0 + wm + i * 16 + q * 4 + r;
        #pragma unroll
        for (int j = 0; j < 4; j++) {
          const int col = n0 + wn + j * 16 + c;
          const size_t idx = (size_t)row * N + col;
          float v = acc[i][j][r] + bj[j];
          if (MODE == 0) ((unsigned short*)outp)[idx] = f2bf(v);
          else           ((unsigned short*)outp)[idx] = f2bf(fmaxf(v, 0.f));
        }
      }
    }
  }
}

template <int MODE, int SWZ>
__global__ __launch_bounds__(256, 2) void gemm_bt(
    const unsigned short* __restrict__ A,
    const unsigned short* __restrict__ Bt,
    const float* __restrict__ bias,
    void* __restrict__ outp,
    int N, int K) {
  __shared__ __align__(16) unsigned short As[2 * 8192];
  __shared__ __align__(16) unsigned short Bs[2 * 8192];
  gemm_core<MODE, SWZ>(A, Bt, bias, outp, N, K, 0, K, As, Bs,
                       blockIdx.x + (blockIdx.y << 5), gridDim.x * gridDim.y);
}

// split-K=2 WITHOUT atomics: z writes its partial to Qz with plain stores.
__global__ __launch_bounds__(256, 2) void gemm_bt_splitk_p(
    const unsigned short* __restrict__ A,
    const unsigned short* __restrict__ Bt,
    float* __restrict__ Q0,
    float* __restrict__ Q1,
    int N, int K) {
  __shared__ __align__(16) unsigned short As[2 * 8192];
  __shared__ __align__(16) unsigned short Bs[2 * 8192];
  const int KH = K >> 1;
  const int kbeg = blockIdx.z * KH;
  gemm_core<5, 1>(A, Bt, nullptr, blockIdx.z ? Q1 : Q0, N, K, kbeg, kbeg + KH,
                  As, Bs, blockIdx.x + (blockIdx.y << 5), gridDim.x * gridDim.y);
}

// d_out += Q0 + Q1 (fp32, 4096x1024). 2048 blocks x 256 thr x f32x4 x 2 iter.
__global__ __launch_bounds__(256) void fold2(
    const float* __restrict__ Q0,
    const float* __restrict__ Q1,
    float* __restrict__ out) {
  int i = (blockIdx.x * 256 + threadIdx.x) * 4;
  #pragma unroll
  for (int it = 0; it < 2; it++) {
    float4 a  = *(const float4*)(out + i);
    float4 q0 = *(const float4*)(Q0 + i);
    float4 q1 = *(const float4*)(Q1 + i);
    a.x += q0.x + q1.x; a.y += q0.y + q1.y;
    a.z += q0.z + q1.z; a.w += q0.w + q1.w;
    *(float4*)(out + i) = a;
    i += 2097152;
  }
}

// ---------------------------------------------------------------------------
// Flash attention, causal + rel_pos bias. K/V double-buffered (R6/R7).
// R11: setprio removed — R10's unattributed regression; our 4-wave
// barrier-locked schedule is m190's null/negative regime.
// ---------------------------------------------------------------------------
__global__ __launch_bounds__(256, 2) void attn_flash(
    const unsigned short* __restrict__ qkv,   // [4096, 3072] bf16 (q|k|v)
    const float* __restrict__ rel_pos,        // [16, 2048] fp32
    unsigned short* __restrict__ o) {         // [4096, 1024] bf16 ([b,s,h,d])
  __shared__ __align__(16) unsigned short Qs[128 * 64];
  __shared__ __align__(16) unsigned short Ks[2][64 * 64];
  __shared__ __align__(16) unsigned short Vs[2][64 * 64];  // transposed [d][kt]
  __shared__ __align__(16) unsigned short Ps[4][32 * 64];
  __shared__ float rps[1024];                              // rel_pos[h,:]*log2e

  const int tid = threadIdx.x;
  const int wave = tid >> 6, lane = tid & 63;
  const int q = lane >> 4, c = lane & 15;

  const int lid = blockIdx.x + (blockIdx.y << 3);
  const int xq = lid & 7, y = lid >> 3;
  const int qt = (y & 32) ? (7 - xq) : xq;
  const int b = y >> 4, h = y & 15;

  const unsigned short* qg = qkv + (size_t)b * 1024 * 3072 + h * 64;
  const unsigned short* kg = qg + 1024;
  const unsigned short* vg = qg + 2048;

  #pragma unroll
  for (int i = 0; i < 4; i++) {
    const int idx = tid + i * 256;
    rps[idx & 1023] = rel_pos[h * 2048 + (idx & 1023)] * 1.44269504f;
  }

  const int sr  = tid >> 3;
  const int cg8 = ((tid & 7) ^ (sr & 7)) << 3;
  #pragma unroll
  for (int it = 0; it < 4; it++)
    cp16(qg + (size_t)(qt * 128 + sr + it * 32) * 3072 + cg8, &Qs[(tid + it * 256) * 8]);

  const int vrow = tid & 63, d0 = (tid >> 6) << 4;
  const int vchunk = vrow >> 3, vlo = vrow & 7;

  // prologue: issue K(0)->Ks[0], V(0)->regs (drained by first barrier)
  cp16(kg + (size_t)sr * 3072 + cg8, &Ks[0][tid * 8]);
  cp16(kg + (size_t)(sr + 32) * 3072 + cg8, &Ks[0][(tid + 256) * 8]);
  union { int4 v; unsigned short u[8]; } va, vb2;
  {
    const unsigned short* vrp = vg + (size_t)vrow * 3072 + d0;
    va.v  = *(const int4*)vrp;
    vb2.v = *(const int4*)(vrp + 8);
  }
  __syncthreads();

  bf16x8 qf[2][2];
  #pragma unroll
  for (int mt = 0; mt < 2; mt++)
    #pragma unroll
    for (int ks = 0; ks < 2; ks++)
      qf[mt][ks] = *(const bf16x8*)&Qs[(wave*32 + mt*16 + c)*64 + ((((ks<<2)+q) ^ (c & 7)) << 3)];

  const f32x4 fzero = {0.f, 0.f, 0.f, 0.f};
  f32x4 O[2][4];
  float l_i[2][4];
  #pragma unroll
  for (int mt = 0; mt < 2; mt++) {
    #pragma unroll
    for (int r = 0; r < 4; r++) l_i[mt][r] = 0.f;
    #pragma unroll
    for (int dt = 0; dt < 4; dt++) O[mt][dt] = fzero;
  }

  unsigned short* Pw = &Ps[wave][0];
  const int i_base = qt * 128 + wave * 32;

  const float sc = 0.125f * 1.44269504f;
  const int kdiag = qt << 1;
  const int nkt = (qt + 1) * 2;

  for (int kt = 0; kt < nkt; kt++) {
    const int buf = kt & 1;

    // 1. all of tile kt's loads have landed (K in LDS, V in regs)
    asm volatile("s_waitcnt vmcnt(0)" ::: "memory");

    // 2. write V(kt) regs -> Vs[buf] (swizzled transpose)
    #pragma unroll
    for (int j = 0; j < 8; j++) {
      const int pos = ((vchunk ^ j) << 3) + vlo;
      Vs[buf][(d0 + j) * 64 + pos]     = va.u[j];
      Vs[buf][(d0 + 8 + j) * 64 + pos] = vb2.u[j];
    }

    // 3. barrier: V writes visible; all waves done reading buf^1
    __syncthreads();

    // 4. prefetch tile kt+1 into buf^1 / regs
    if (kt + 1 < nkt) {
      cp16(kg + (size_t)((kt + 1) * 64 + sr) * 3072 + cg8, &Ks[buf ^ 1][tid * 8]);
      cp16(kg + (size_t)((kt + 1) * 64 + sr + 32) * 3072 + cg8, &Ks[buf ^ 1][(tid + 256) * 8]);
      const unsigned short* vrp = vg + (size_t)((kt + 1) * 64 + vrow) * 3072 + d0;
      va.v  = *(const int4*)vrp;
      vb2.v = *(const int4*)(vrp + 8);
    }

    // 5. compute on buf
    f32x4 S[2][4];
    #pragma unroll
    for (int mt = 0; mt < 2; mt++)
      #pragma unroll
      for (int nt = 0; nt < 4; nt++) S[mt][nt] = fzero;
    #pragma unroll
    for (int ks = 0; ks < 2; ks++) {
      const int sw = (((ks << 2) + q) ^ (c & 7)) << 3;
      bf16x8 kb[4];
      #pragma unroll
      for (int nt = 0; nt < 4; nt++) kb[nt] = *(const bf16x8*)&Ks[buf][(nt*16 + c)*64 + sw];
      #pragma unroll
      for (int mt = 0; mt < 2; mt++)
        #pragma unroll
        for (int nt = 0; nt < 4; nt++)
          S[mt][nt] = __builtin_amdgcn_mfma_f32_16x16x32_bf16(qf[mt][ks], kb[nt], S[mt][nt], 0, 0, 0);
    }

    if (kt < kdiag) {
      #pragma unroll
      for (int mt = 0; mt < 2; mt++) {
        #pragma unroll
        for (int r = 0; r < 4; r++) {
          const int i_ = i_base + mt * 16 + q * 4 + r;
          const int prow = (mt * 16 + q * 4 + r) * 64;
          const int rsw  = (q * 4 + r) & 7;
          float s = 0.f;
          #pragma unroll
          for (int nt = 0; nt < 4; nt++) {
            const int j_ = kt * 64 + nt * 16 + c;
            const float p = exp2f(fmaf(S[mt][nt][r], sc, rps[i_ - j_]));
            s += p;
            Pw[prow + ((((nt << 1) + (c >> 3)) ^ rsw) << 3) + (c & 7)] = f2bf_fast(p);
          }
          l_i[mt][r] += s;
        }
      }
    } else {
      #pragma unroll
      for (int mt = 0; mt < 2; mt++) {
        #pragma unroll
        for (int r = 0; r < 4; r++) {
          const int i_ = i_base + mt * 16 + q * 4 + r;
          const int prow = (mt * 16 + q * 4 + r) * 64;
          const int rsw  = (q * 4 + r) & 7;
          float s = 0.f;
          #pragma unroll
          for (int nt = 0; nt < 4; nt++) {
            const int j_ = kt * 64 + nt * 16 + c;
            const int d_ = i_ - j_;
            const float p = (d_ >= 0)
                ? exp2f(fmaf(S[mt][nt][r], sc, rps[d_ & 1023])) : 0.f;
            s += p;
            Pw[prow + ((((nt << 1) + (c >> 3)) ^ rsw) << 3) + (c & 7)] = f2bf_fast(p);
          }
          l_i[mt][r] += s;
        }
      }
    }

    asm volatile("s_waitcnt lgkmcnt(0)" ::: "memory");

    #pragma unroll
    for (int ks = 0; ks < 2; ks++) {
      const int sw = (((ks << 2) + q) ^ (c & 7)) << 3;
      bf16x8 pa[2], vb[4];
      #pragma unroll
      for (int mt = 0; mt < 2; mt++) pa[mt] = *(const bf16x8*)&Pw[(mt*16 + c)*64 + sw];
      #pragma unroll
      for (int dt = 0; dt < 4; dt++) vb[dt] = *(const bf16x8*)&Vs[buf][(dt*16 + c)*64 + sw];
      #pragma unroll
      for (int mt = 0; mt < 2; mt++)
        #pragma unroll
        for (int dt = 0; dt < 4; dt++)
          O[mt][dt] = __builtin_amdgcn_mfma_f32_16x16x32_bf16(pa[mt], vb[dt], O[mt][dt], 0, 0, 0);
    }
  }

  #pragma unroll
  for (int mt = 0; mt < 2; mt++) {
    #pragma unroll
    for (int r = 0; r < 4; r++) {
      float l = l_i[mt][r];
      l += __shfl_xor(l, 1, 64);
      l += __shfl_xor(l, 2, 64);
      l += __shfl_xor(l, 4, 64);
      l += __shfl_xor(l, 8, 64);
      const float inv = 1.0f / l;
      const int i_ = i_base + mt * 16 + q * 4 + r;
      unsigned short* orow = o + (size_t)(b * 1024 + i_) * 1024 + h * 64 + c;
      #pragma unroll
      for (int dt = 0; dt < 4; dt++) orow[dt * 16] = f2bf(O[mt][dt][r] * inv);
    }
  }
}

// ---------------------------------------------------------------------------
// Launch. Workspace ~81 MB, aliased.
// Out-proj partials: P0 = qkvb head (qkv dead after attn), P1 = x2 scratch.
// MLP-down partials: Q0 = [ipw_b..w1_b] (dead), Q1 = x2 (dead after fold_ln).
// ---------------------------------------------------------------------------
extern "C" void kernel_launch(void* const* d_in, const int* in_sizes, int n_in,
                              void* d_out, int out_size, void* d_ws, size_t ws_size,
                              hipStream_t stream) {
  (void)in_sizes; (void)n_in; (void)out_size; (void)ws_size;
  const float* x    = (const float*)d_in[0];
  const float* rel  = (const float*)d_in[1];
  const float* ipw  = (const float*)d_in[2];
  const float* ipb  = (const float*)d_in[3];
  const float* outw = (const float*)d_in[4];
  const float* outb = (const float*)d_in[5];
  const float* w1   = (const float*)d_in[6];
  const float* b1   = (const float*)d_in[7];
  const float* w2   = (const float*)d_in[8];
  const float* b2   = (const float*)d_in[9];
  const float* ln1g = (const float*)d_in[10];
  const float* ln1b = (const float*)d_in[11];
  const float* ln2g = (const float*)d_in[12];
  const float* ln2b = (const float*)d_in[13];

  // workspace layout (elements), aliased:
  unsigned short* ipw_b  = (unsigned short*)d_ws;            // 3072*1024
  unsigned short* outw_b = ipw_b  + (size_t)3072 * 1024;     // 1024*1024
  unsigned short* w1_b   = outw_b + (size_t)1024 * 1024;     // 4096*1024
  unsigned short* w2_b   = w1_b   + (size_t)4096 * 1024;     // 1024*4096
  unsigned short* xn     = w2_b   + (size_t)1024 * 4096;     // 4096*1024 (also xm)
  unsigned short* qkvb   = xn     + (size_t)4096 * 1024;     // 4096*3072 ┐
  unsigned short* ob     = qkvb   + (size_t)4096 * 3072;     // 4096*1024 ┴ hb aliases both
  unsigned short* hb     = qkvb;                             // 4096*4096 (after fold_ln)
  unsigned short* xm     = xn;                               // after QKV consumed xn
  float*          x2     = (float*)(ob + (size_t)4096 * 1024);  // 4096*1024 f32 scratch
  // out-proj partials (dead regions at out-proj launch):
  float*          P0     = (float*)qkvb;   // qkv dead after attn; ob untouched
  float*          P1     = x2;
  // MLP-down partials (dead regions at down launch):
  float*          Q0     = (float*)d_ws;   // ipw_b+outw_b+w1_b = 16.78 MB
  float*          Q1     = x2;
  // total = 81 MB

  // fused: weight converts + ln1 (serial, proven)
  cvt_ln1<<<16384, 256, 0, stream>>>(ipw, outw, w1, w2, ipw_b, outw_b, w1_b, w2_b,
                                     x, ln1g, ln1b, xn);

  // QKV proj (swizzled)
  gemm_bt<0, 1><<<dim3(32, 24), 256, 0, stream>>>(xn, ipw_b, ipb, qkvb, 3072, 1024);

  attn_flash<<<dim3(8, 64), 256, 0, stream>>>(qkvb, rel, ob);

  // attn out proj: partials P0/P1 (split-K=2, no atomics, swizzled)
  gemm_bt_splitk_p<<<dim3(32, 8, 2), 256, 0, stream>>>(ob, outw_b, P0, P1, 1024, 1024);

  // fold + ln2 + seed: x2 = x + outb + P0 + P1; xm = ln2(x2); d_out = x2 + b2
  fold_ln<<<4096, 256, 0, stream>>>(x, P0, P1, outb, ln2g, ln2b, xm, b2, (float*)d_out);

  // MLP up (linear mapping — R9 A/B: swizzle cost it 3us here)
  gemm_bt<2, 0><<<dim3(32, 32), 256, 0, stream>>>(xm, w1_b, b1, hb, 4096, 1024);

  // MLP down, atomic-free: partials Q0/Q1, then d_out += Q0 + Q1
  gemm_bt_splitk_p<<<dim3(32, 8, 2), 256, 0, stream>>>(hb, w2_b, Q0, Q1, 1024, 4096);
  fold2<<<2048, 256, 0, stream>>>(Q0, Q1, (float*)d_out);
}